// Round 16
// baseline (180.288 us; speedup 1.0000x reference)
//
#include <hip/hip_runtime.h>
#include <hip/hip_bf16.h>

// MHA: B=2, S=2048, D=1024, H=16, dk=64.  M = B*S = 4096.
// ws layout (MB):
//   0-8   Wt_q|Wt_k|Wt_v|Wt_o  bf16 [out][in] (2MB each)
//   8-16  Q2 [M,1024] bf16 (pre-scaled 0.125*log2e)
//  16-24  K2 [M,1024] bf16
//  24-32  Vt [B,H,64,S] bf16
//  32-40  ctx [M,1024] bf16
//  40-64  X2q|X2k|X2v bf16 [M,1024] (8MB each; dead after proj)
//  40-56  Opart bf16 [2][65536][64]  (overlaps X2q/X2k - written later)
//  56-56.5 lpart f32 [2][65536]      (overlaps X2v - written later)

typedef __bf16 bf16x8 __attribute__((ext_vector_type(8)));
typedef float  f32x4  __attribute__((ext_vector_type(4)));
typedef float  f32x4v __attribute__((ext_vector_type(4)));
typedef unsigned int u32x4 __attribute__((ext_vector_type(4)));

#define DEVI __device__ __forceinline__
#define SWZ(row, cb) ((cb) ^ (((row) & 7) << 4))

#define GLOAD16(gsrc, ldst)                                                    \
    __builtin_amdgcn_global_load_lds(                                          \
        (const __attribute__((address_space(1))) unsigned int*)(gsrc),         \
        (__attribute__((address_space(3))) unsigned int*)(ldst), 16, 0, 0)

// raw barrier: NO implicit vmcnt(0) drain (unlike __syncthreads)
#define BAR()        asm volatile("s_barrier" ::: "memory")
#define WAIT_LGKM0() asm volatile("s_waitcnt lgkmcnt(0)" ::: "memory")
#define WAIT_VM0()   asm volatile("s_waitcnt vmcnt(0)" ::: "memory")
#define WAIT_VM2()   asm volatile("s_waitcnt vmcnt(2)" ::: "memory")

static DEVI unsigned short f2bf(float f) {
    __hip_bfloat16 h = __float2bfloat16(f);
    return __builtin_bit_cast(unsigned short, h);
}
// single-instruction packed f32->bf16 (RNE), T12 recipe
static DEVI unsigned int cvt2(float lo, float hi) {
    unsigned int r;
    asm("v_cvt_pk_bf16_f32 %0, %1, %2" : "=v"(r) : "v"(lo), "v"(hi));
    return r;
}
static DEVI float bf2f(unsigned int lo16) {
    unsigned int x = lo16 << 16;
    return __builtin_bit_cast(float, x);
}
static DEVI bf16x8 ldsRead(const char* p) {
    return __builtin_bit_cast(bf16x8, *(const uint4*)p);
}

// ---------------------------------------------------------------------------
// Kernel 0: x f32 -> bf16, NON-TEMPORAL both directions (native ext_vector
// types — clang's nontemporal builtins reject HIP_vector_type wrappers).
// ---------------------------------------------------------------------------
__global__ __launch_bounds__(256) void xconv_kernel(
    const float* x0, const float* x1, const float* x2,
    unsigned short* y0, unsigned short* y1, unsigned short* y2)
{
    const int z = blockIdx.y;
    const float* x = (z == 0) ? x0 : (z == 1) ? x1 : x2;
    unsigned short* y = (z == 0) ? y0 : (z == 1) ? y1 : y2;
    size_t idx = ((size_t)blockIdx.x * 256 + threadIdx.x) * 8;
    f32x4v a = __builtin_nontemporal_load((const f32x4v*)(x + idx));
    f32x4v b = __builtin_nontemporal_load((const f32x4v*)(x + idx) + 1);
    u32x4 pk;
    pk.x = cvt2(a.x, a.y);
    pk.y = cvt2(a.z, a.w);
    pk.z = cvt2(b.x, b.y);
    pk.w = cvt2(b.z, b.w);
    __builtin_nontemporal_store(pk, (u32x4*)(y + idx));
}

// ---------------------------------------------------------------------------
// Kernel 1: weight transpose + bf16 convert
// ---------------------------------------------------------------------------
__global__ __launch_bounds__(256) void wtrans_kernel(
    const float* w0, const float* w1, const float* w2, const float* w3,
    unsigned short* t0, unsigned short* t1, unsigned short* t2, unsigned short* t3)
{
    __shared__ unsigned short tile[64][80];
    const int z = blockIdx.z;
    const float* w = (z == 0) ? w0 : (z == 1) ? w1 : (z == 2) ? w2 : w3;
    unsigned short* wt = (z == 0) ? t0 : (z == 1) ? t1 : (z == 2) ? t2 : t3;
    const int n0 = blockIdx.x * 64, k0 = blockIdx.y * 64;
    const int t = threadIdx.x;
#pragma unroll
    for (int i = 0; i < 4; i++) {
        int chunk = t + i * 256;
        int row = chunk >> 4, c4 = chunk & 15;
        float4 v = *(const float4*)(w + (size_t)(k0 + row) * 1024 + n0 + c4 * 4);
        tile[c4 * 4 + 0][row] = f2bf(v.x);
        tile[c4 * 4 + 1][row] = f2bf(v.y);
        tile[c4 * 4 + 2][row] = f2bf(v.z);
        tile[c4 * 4 + 3][row] = f2bf(v.w);
    }
    __syncthreads();
#pragma unroll
    for (int i = 0; i < 2; i++) {
        int idx = t + i * 256;
        int row = idx >> 3, ch = idx & 7;
        uint4 vv = *(const uint4*)(&tile[row][ch * 8]);
        *(uint4*)(wt + (size_t)(n0 + row) * 1024 + k0 + ch * 8) = vv;
    }
}

// ---------------------------------------------------------------------------
// Kernel 2: QKV projections — pure-bf16 m97 structure (A pre-converted).
// Tile 128x128, BK=64, 32KB LDS, 4 blocks/CU, 2 raw barriers/iter.
// ---------------------------------------------------------------------------
__global__ __launch_bounds__(256, 4) void gemm_proj_kernel(
    const unsigned short* x0, const unsigned short* x1, const unsigned short* x2,
    const unsigned short* wt0, const unsigned short* wt1, const unsigned short* wt2,
    const float* b0, const float* b1, const float* b2,
    unsigned short* y0, unsigned short* y1, unsigned short* y2)
{
    __shared__ __align__(16) char sm[32768];
    char* As = sm;
    char* Bs = sm + 16384;
    const int i = blockIdx.x;
    const int xcd = i & 7, j = i >> 3;          // j 0..95
    const int panel = xcd * 12 + (j >> 3);      // 96 panels = 3z x 32m
    const int z = panel >> 5, mblk = panel & 31;
    const int n0 = (j & 7) * 128, m0 = mblk * 128;

    const unsigned short* X = (z == 0) ? x0 : (z == 1) ? x1 : x2;
    const unsigned short* Wt = (z == 0) ? wt0 : (z == 1) ? wt1 : wt2;
    const float* bias = (z == 0) ? b0 : (z == 1) ? b1 : b2;
    unsigned short* Y = (z == 0) ? y0 : (z == 1) ? y1 : y2;
    const float scale = (z == 0) ? 0.125f * 1.44269504f : 1.0f;
    const int t = threadIdx.x, w = t >> 6, l = t & 63, l15 = l & 15, l4 = l >> 4;
    const int wr = w >> 1, wc = w & 1;
    const char* Ab = (const char*)X;
    const char* Bb = (const char*)Wt;

    f32x4 acc[4][4];
#pragma unroll
    for (int mr = 0; mr < 4; mr++)
#pragma unroll
        for (int nc = 0; nc < 4; nc++) acc[mr][nc] = f32x4{0.f, 0.f, 0.f, 0.f};

#pragma unroll 1
    for (int k = 0; k < 16; ++k) {
        const int k0 = k * 64;
        BAR();
#pragma unroll
        for (int jj = 0; jj < 4; jj++) {
            int o = w * 4096 + jj * 1024 + l * 16;
            int row = o >> 7, cb = (o >> 4) & 7;
            int csw = cb ^ (row & 7);
            GLOAD16(Ab + ((size_t)(m0 + row) * 1024 + k0 + csw * 8) * 2,
                    As + w * 4096 + jj * 1024);
        }
#pragma unroll
        for (int jj = 0; jj < 4; jj++) {
            int o = w * 4096 + jj * 1024 + l * 16;
            int row = o >> 7, cb = (o >> 4) & 7;
            int csw = cb ^ (row & 7);
            GLOAD16(Bb + ((size_t)(n0 + row) * 1024 + k0 + csw * 8) * 2,
                    Bs + w * 4096 + jj * 1024);
        }
        WAIT_VM0();
        BAR();

        bf16x8 af[4][2], bfr[4][2];
#pragma unroll
        for (int mr = 0; mr < 4; mr++) {
            int row = wr * 64 + mr * 16 + l15;
#pragma unroll
            for (int kf = 0; kf < 2; kf++)
                af[mr][kf] = ldsRead(As + row * 128 + SWZ(row, kf * 64 + l4 * 16));
        }
#pragma unroll
        for (int nc = 0; nc < 4; nc++) {
            int row = wc * 64 + nc * 16 + l15;
#pragma unroll
            for (int kf = 0; kf < 2; kf++)
                bfr[nc][kf] = ldsRead(Bs + row * 128 + SWZ(row, kf * 64 + l4 * 16));
        }
        __builtin_amdgcn_s_setprio(1);
#pragma unroll
        for (int kf = 0; kf < 2; kf++)
#pragma unroll
            for (int mr = 0; mr < 4; mr++)
#pragma unroll
                for (int nc = 0; nc < 4; nc++)
                    acc[mr][nc] = __builtin_amdgcn_mfma_f32_16x16x32_bf16(
                        af[mr][kf], bfr[nc][kf], acc[mr][nc], 0, 0, 0);
        __builtin_amdgcn_s_setprio(0);
    }

    WAIT_LGKM0();
    BAR();  // all waves done with sm before reuse as epilogue buffer
    char* Es = sm;  // 32KB: [128][128] bf16
    if (z < 2) {
#pragma unroll
        for (int nc = 0; nc < 4; nc++) {
            float bv = bias[n0 + wc * 64 + nc * 16 + l15];
#pragma unroll
            for (int mr = 0; mr < 4; mr++) {
#pragma unroll
                for (int r = 0; r < 2; r++) {
                    int mloc = wr * 64 + mr * 16 + l4 * 4 + r * 2;
                    int nloc = wc * 64 + nc * 16 + l15;
                    unsigned int pk = cvt2((acc[mr][nc][r * 2] + bv) * scale,
                                           (acc[mr][nc][r * 2 + 1] + bv) * scale);
                    *(unsigned short*)(Es + mloc * 256 + nloc * 2) =
                        (unsigned short)(pk & 0xffff);
                    *(unsigned short*)(Es + (mloc + 1) * 256 + nloc * 2) =
                        (unsigned short)(pk >> 16);
                }
            }
        }
        WAIT_LGKM0();
        BAR();
#pragma unroll
        for (int ii = 0; ii < 8; ii++) {
            int idx = t + ii * 256, row = idx >> 4, ch = idx & 15;
            *(uint4*)((char*)Y + ((size_t)(m0 + row) * 1024 + n0 + ch * 8) * 2) =
                *(const uint4*)(Es + row * 256 + ch * 16);
        }
    } else {
#pragma unroll
        for (int nc = 0; nc < 4; nc++) {
            float bv = bias[n0 + wc * 64 + nc * 16 + l15];
#pragma unroll
            for (int mr = 0; mr < 4; mr++) {
#pragma unroll
                for (int r = 0; r < 2; r++) {
                    int mloc = wr * 64 + mr * 16 + l4 * 4 + r * 2;
                    int nloc = wc * 64 + nc * 16 + l15;
                    unsigned int pk = cvt2(acc[mr][nc][r * 2] + bv,
                                           acc[mr][nc][r * 2 + 1] + bv);
                    // transpose layout [128 n][128 m]: adjacent m adjacent u16
                    *(unsigned int*)(Es + nloc * 256 + mloc * 2) = pk;
                }
            }
        }
        WAIT_LGKM0();
        BAR();
        const int bb = m0 >> 11, s0 = m0 & 2047;
#pragma unroll
        for (int ii = 0; ii < 8; ii++) {
            int idx = t + ii * 256, row = idx >> 4, ch = idx & 15;
            int col = n0 + row, h = col >> 6, d = col & 63;
            *(uint4*)((char*)Y +
                      (((size_t)((bb * 16 + h) * 64 + d)) * 2048 + s0 + ch * 8) * 2) =
                *(const uint4*)(Es + row * 256 + ch * 16);
        }
    }
}

// ---------------------------------------------------------------------------
// Kernel 3: flash attention, SPLIT-K (round 11, unchanged).
// ---------------------------------------------------------------------------
__global__ __launch_bounds__(256, 4) void attn_kernel(
    const unsigned short* Q2, const unsigned short* K2, const unsigned short* VT,
    unsigned short* Opart, float* lpart)
{
    __shared__ __align__(16) char sm[40960];
    char* Pall = sm;                    // 16KB: per-wave P (4KB each)
    char* K0s = sm + 16384;
    char* K1s = sm + 24576;
    char* Vs  = sm + 32768;
    const int t = threadIdx.x, w = t >> 6, l = t & 63, l15 = l & 15, l4 = l >> 4;
    char* Ps = Pall + w * 4096;         // 32 rows x 128B per wave

    // mapping: 8 XCD x 4 heads x (16 qblk x 2 khalf)
    const int i = blockIdx.x;
    const int xcd = i & 7, j = i >> 3;          // j 0..127
    const int bh = xcd * 4 + (j >> 5);
    const int jj = j & 31, qblk = jj >> 1, kh = jj & 1;
    const int b = bh >> 4, h = bh & 15;
    const int q0 = qblk * 128;
    const char* Qb = (const char*)(Q2 + ((size_t)(b * 2048 + q0)) * 1024 + h * 64);
    const char* Kb = (const char*)(K2 + ((size_t)(b * 2048)) * 1024 + h * 64);
    const char* Vb = (const char*)(VT + (size_t)bh * 64 * 2048);

    int kGO[2], vGO[2];
#pragma unroll
    for (int jj2 = 0; jj2 < 2; jj2++) {
        int row = w * 16 + jj2 * 8 + (l >> 3);
        int ch = (l & 7) ^ (row & 7);
        kGO[jj2] = row * 2048 + ch * 16;
        vGO[jj2] = row * 4096 + ch * 16;
    }
    int kRO[4][2];
#pragma unroll
    for (int cc = 0; cc < 4; cc++) {
        int row = cc * 16 + l15;
#pragma unroll
        for (int kf = 0; kf < 2; kf++)
            kRO[cc][kf] = row * 128 + SWZ(row, kf * 64 + l4 * 16);
    }
    int pWO[2][4], pRO[2][2];
#pragma unroll
    for (int qi = 0; qi < 2; qi++) {
        int row = qi * 16 + l15;
#pragma unroll
        for (int cc = 0; cc < 4; cc++) {
            int c = (cc * 2 + (l4 >> 1)) ^ (l15 & 7);
            pWO[qi][cc] = row * 128 + c * 16 + (l4 & 1) * 8;
        }
#pragma unroll
        for (int kf = 0; kf < 2; kf++)
            pRO[qi][kf] = row * 128 + SWZ(row, kf * 64 + l4 * 16);
    }

#define STAGE_K(TT, Kdst)                                                      \
    do {                                                                       \
        int kk0 = (TT) * 64;                                                   \
        _Pragma("unroll") for (int s2 = 0; s2 < 2; s2++)                       \
            GLOAD16(Kb + (size_t)(kk0 * 2048 + kGO[s2]),                       \
                    (Kdst) + w * 2048 + s2 * 1024);                            \
    } while (0)
#define STAGE_V(TT)                                                            \
    do {                                                                       \
        int kk0 = (TT) * 64;                                                   \
        _Pragma("unroll") for (int s2 = 0; s2 < 2; s2++)                       \
            GLOAD16(Vb + (size_t)(kk0 * 2 + vGO[s2]),                          \
                    Vs + w * 2048 + s2 * 1024);                                \
    } while (0)

    bf16x8 qf[2][2];
#pragma unroll
    for (int qi = 0; qi < 2; qi++) {
        int row = w * 32 + qi * 16 + l15;
#pragma unroll
        for (int kf = 0; kf < 2; kf++)
            qf[qi][kf] = __builtin_bit_cast(
                bf16x8, *(const uint4*)(Qb + (size_t)row * 2048 + kf * 64 + l4 * 16));
    }

    const int tbase = kh * 16;
    STAGE_K(tbase + (qblk & 15), K0s);
    STAGE_V(tbase + (qblk & 15));
    WAIT_VM0();
    BAR();

    bf16x8 ones;
#pragma unroll
    for (int e = 0; e < 8; e++) ones[e] = (__bf16)1.0f;

    f32x4 o[2][4], ol[2];
#pragma unroll
    for (int qi = 0; qi < 2; qi++) {
#pragma unroll
        for (int c = 0; c < 4; c++) o[qi][c] = f32x4{0.f, 0.f, 0.f, 0.f};
        ol[qi] = f32x4{0.f, 0.f, 0.f, 0.f};
    }

#pragma unroll 1
    for (int it = 0; it < 16; it++) {
        char* Kc = (it & 1) ? K1s : K0s;
        char* Kn = (it & 1) ? K0s : K1s;
        if (it < 15) STAGE_K(tbase + ((qblk + it + 1) & 15), Kn);

        f32x4 sacc[2][4];
#pragma unroll
        for (int qi = 0; qi < 2; qi++)
#pragma unroll
            for (int c = 0; c < 4; c++) sacc[qi][c] = f32x4{0.f, 0.f, 0.f, 0.f};
        __builtin_amdgcn_s_setprio(1);
#pragma unroll
        for (int cc = 0; cc < 4; cc++)
#pragma unroll
            for (int kf = 0; kf < 2; kf++) {
                bf16x8 kfrag = ldsRead(Kc + kRO[cc][kf]);
#pragma unroll
                for (int qi = 0; qi < 2; qi++)
                    sacc[qi][cc] = __builtin_amdgcn_mfma_f32_16x16x32_bf16(
                        kfrag, qf[qi][kf], sacc[qi][cc], 0, 0, 0);
            }
        __builtin_amdgcn_s_setprio(0);

#pragma unroll
        for (int qi = 0; qi < 2; qi++)
#pragma unroll
            for (int cc = 0; cc < 4; cc++)
#pragma unroll
                for (int r = 0; r < 4; r++)
                    sacc[qi][cc][r] = __builtin_amdgcn_exp2f(sacc[qi][cc][r]);

#pragma unroll
        for (int qi = 0; qi < 2; qi++)
#pragma unroll
            for (int cc = 0; cc < 4; cc++) {
                uint2 pk = {cvt2(sacc[qi][cc][0], sacc[qi][cc][1]),
                            cvt2(sacc[qi][cc][2], sacc[qi][cc][3])};
                *(uint2*)(Ps + pWO[qi][cc]) = pk;
            }
        asm volatile("" ::: "memory");
        bf16x8 pf[2][2];
#pragma unroll
        for (int qi = 0; qi < 2; qi++)
#pragma unroll
            for (int kf = 0; kf < 2; kf++)
                pf[qi][kf] = ldsRead(Ps + pRO[qi][kf]);

        if (it < 15) { WAIT_VM2(); } else { WAIT_VM0(); }
        BAR();

        __builtin_amdgcn_s_setprio(1);
#pragma unroll
        for (int dd = 0; dd < 4; dd++)
#pragma unroll
            for (int kf = 0; kf < 2; kf++) {
                bf16x8 vfrag = ldsRead(Vs + kRO[dd][kf]);
#pragma unroll
                for (int qi = 0; qi < 2; qi++)
                    o[qi][dd] = __builtin_amdgcn_mfma_f32_16x16x32_bf16(
                        vfrag, pf[qi][kf], o[qi][dd], 0, 0, 0);
            }
#pragma unroll
        for (int qi = 0; qi < 2; qi++)
#pragma unroll
            for (int kf = 0; kf < 2; kf++)
                ol[qi] = __builtin_amdgcn_mfma_f32_16x16x32_bf16(
                    ones, pf[qi][kf], ol[qi], 0, 0, 0);
        __builtin_amdgcn_s_setprio(0);

        WAIT_LGKM0();
        BAR();
        if (it < 15) {
            STAGE_V(tbase + ((qblk + it + 1) & 15));
            WAIT_VM2();
            BAR();
        }
    }
#undef STAGE_K
#undef STAGE_V

    const size_t qgbase = (size_t)bh * 2048 + q0 + w * 32;
#pragma unroll
    for (int qi = 0; qi < 2; qi++) {
        size_t qg = qgbase + qi * 16 + l15;
        unsigned short* orow = Opart + ((size_t)kh * 65536 + qg) * 64;
#pragma unroll
        for (int dd = 0; dd < 4; dd++) {
            uint2 pk = {cvt2(o[qi][dd][0], o[qi][dd][1]),
                        cvt2(o[qi][dd][2], o[qi][dd][3])};
            *(uint2*)(orow + dd * 16 + l4 * 4) = pk;
        }
        if (l4 == 0) lpart[(size_t)kh * 65536 + qg] = ol[qi][0];
    }
}

// ---------------------------------------------------------------------------
// Kernel 3b: combine split-K partials -> ctx bf16 [B,S,1024]
// ---------------------------------------------------------------------------
__global__ __launch_bounds__(256) void reduce_kernel(
    const unsigned short* Op, const float* lp, unsigned short* ctx)
{
    int idx = blockIdx.x * 256 + threadIdx.x;   // 524288 total
    int qg = idx >> 3, c8 = idx & 7;
    uint4 a = *(const uint4*)(Op + (size_t)qg * 64 + c8 * 8);
    uint4 bq = *(const uint4*)(Op + (size_t)65536 * 64 + (size_t)qg * 64 + c8 * 8);
    float rinv = 1.0f / (lp[qg] + lp[65536 + qg]);
    const unsigned int* pa = (const unsigned int*)&a;
    const unsigned int* pb = (const unsigned int*)&bq;
    unsigned int outp[4];
#pragma unroll
    for (int j = 0; j < 4; j++) {
        float s0 = (bf2f(pa[j] & 0xffff) + bf2f(pb[j] & 0xffff)) * rinv;
        float s1 = (bf2f(pa[j] >> 16) + bf2f(pb[j] >> 16)) * rinv;
        outp[j] = cvt2(s0, s1);
    }
    int bh = qg >> 11, s = qg & 2047, b = bh >> 4, h = bh & 15;
    *(uint4*)(ctx + ((size_t)(b * 2048 + s)) * 1024 + h * 64 + c8 * 8) =
        *(const uint4*)outp;
}

// ---------------------------------------------------------------------------
// Kernel 4: output projection, m97 structure (unchanged).
// ---------------------------------------------------------------------------
__global__ __launch_bounds__(256, 3) void gemm_out_kernel(
    const unsigned short* ctx, const unsigned short* wto, const float* bias, float* out)
{
    __shared__ __align__(16) char As[16384];
    __shared__ __align__(16) char Bs[16384];
    const int i = blockIdx.x;
    const int xcd = i & 7, j = i >> 3;          // j 0..31
    const int mpanel = xcd * 4 + (j >> 3);
    const int n0 = (j & 7) * 128, m0 = mpanel * 128;
    const int t = threadIdx.x, w = t >> 6, l = t & 63, l15 = l & 15, l4 = l >> 4;
    const int wr = w >> 1, wc = w & 1;
    const char* Ab = (const char*)ctx;
    const char* Bb = (const char*)wto;

    f32x4 acc[4][4];
#pragma unroll
    for (int mr = 0; mr < 4; mr++)
#pragma unroll
        for (int nc = 0; nc < 4; nc++) acc[mr][nc] = f32x4{0.f, 0.f, 0.f, 0.f};

#pragma unroll 1
    for (int k = 0; k < 16; ++k) {
        const int k0 = k * 64;
        BAR();
#pragma unroll
        for (int jj = 0; jj < 4; jj++) {
            int o = w * 4096 + jj * 1024 + l * 16;
            int row = o >> 7, cb = (o >> 4) & 7;
            int csw = cb ^ (row & 7);
            GLOAD16(Ab + ((size_t)(m0 + row) * 1024 + k0 + csw * 8) * 2,
                    As + w * 4096 + jj * 1024);
        }
#pragma unroll
        for (int jj = 0; jj < 4; jj++) {
            int o = w * 4096 + jj * 1024 + l * 16;
            int row = o >> 7, cb = (o >> 4) & 7;
            int csw = cb ^ (row & 7);
            GLOAD16(Bb + ((size_t)(n0 + row) * 1024 + k0 + csw * 8) * 2,
                    Bs + w * 4096 + jj * 1024);
        }
        WAIT_VM0();
        BAR();

        bf16x8 af[4][2], bfr[4][2];
#pragma unroll
        for (int mr = 0; mr < 4; mr++) {
            int row = wr * 64 + mr * 16 + l15;
#pragma unroll
            for (int kf = 0; kf < 2; kf++)
                af[mr][kf] = ldsRead(As + row * 128 + SWZ(row, kf * 64 + l4 * 16));
        }
#pragma unroll
        for (int nc = 0; nc < 4; nc++) {
            int row = wc * 64 + nc * 16 + l15;
#pragma unroll
            for (int kf = 0; kf < 2; kf++)
                bfr[nc][kf] = ldsRead(Bs + row * 128 + SWZ(row, kf * 64 + l4 * 16));
        }
        __builtin_amdgcn_s_setprio(1);
#pragma unroll
        for (int kf = 0; kf < 2; kf++)
#pragma unroll
            for (int mr = 0; mr < 4; mr++)
#pragma unroll
                for (int nc = 0; nc < 4; nc++)
                    acc[mr][nc] = __builtin_amdgcn_mfma_f32_16x16x32_bf16(
                        af[mr][kf], bfr[nc][kf], acc[mr][nc], 0, 0, 0);
        __builtin_amdgcn_s_setprio(0);
    }

#pragma unroll
    for (int nc = 0; nc < 4; nc++) {
        int col = n0 + wc * 64 + nc * 16 + l15;
        float bv = bias[col];
#pragma unroll
        for (int mr = 0; mr < 4; mr++)
#pragma unroll
            for (int r = 0; r < 4; r++) {
                int m = m0 + wr * 64 + mr * 16 + l4 * 4 + r;
                out[(size_t)m * 1024 + col] = acc[mr][nc][r] + bv;
            }
    }
}

// ---------------------------------------------------------------------------
extern "C" void kernel_launch(void* const* d_in, const int* in_sizes, int n_in,
                              void* d_out, int out_size, void* d_ws, size_t ws_size,
                              hipStream_t stream)
{
    (void)in_sizes; (void)n_in; (void)out_size; (void)ws_size;
    const float* q  = (const float*)d_in[0];
    const float* k  = (const float*)d_in[1];
    const float* v  = (const float*)d_in[2];
    const float* wq = (const float*)d_in[3];
    const float* bq = (const float*)d_in[4];
    const float* wk = (const float*)d_in[5];
    const float* bk = (const float*)d_in[6];
    const float* wv = (const float*)d_in[7];
    const float* bv = (const float*)d_in[8];
    const float* wo = (const float*)d_in[9];
    const float* bo = (const float*)d_in[10];

    char* ws = (char*)d_ws;
    const size_t MB = 1u << 20;
    unsigned short* WTq = (unsigned short*)(ws + 0 * MB);
    unsigned short* WTk = (unsigned short*)(ws + 2 * MB);
    unsigned short* WTv = (unsigned short*)(ws + 4 * MB);
    unsigned short* WTo = (unsigned short*)(ws + 6 * MB);
    unsigned short* Q2  = (unsigned short*)(ws + 8 * MB);
    unsigned short* K2  = (unsigned short*)(ws + 16 * MB);
    unsigned short* VT  = (unsigned short*)(ws + 24 * MB);
    unsigned short* CTX = (unsigned short*)(ws + 32 * MB);
    // X2 buffers (dead after proj) overlap Opart/lpart (written by attn later)
    unsigned short* X2q = (unsigned short*)(ws + 40 * MB);
    unsigned short* X2k = (unsigned short*)(ws + 48 * MB);
    unsigned short* X2v = (unsigned short*)(ws + 56 * MB);
    unsigned short* OPART = (unsigned short*)(ws + 40 * MB);
    float*          LPART = (float*)(ws + 56 * MB);

    wtrans_kernel<<<dim3(16, 16, 4), 256, 0, stream>>>(wq, wk, wv, wo, WTq, WTk, WTv, WTo);
    xconv_kernel<<<dim3(2048, 3), 256, 0, stream>>>(q, k, v, X2q, X2k, X2v);
    gemm_proj_kernel<<<768, 256, 0, stream>>>(X2q, X2k, X2v, WTq, WTk, WTv,
                                              bq, bk, bv, Q2, K2, VT);
    attn_kernel<<<1024, 256, 0, stream>>>(Q2, K2, VT, OPART, LPART);
    reduce_kernel<<<2048, 256, 0, stream>>>(OPART, LPART, CTX);
    gemm_out_kernel<<<256, 256, 0, stream>>>(CTX, WTo, bo, (float*)d_out);
}

// Round 17
// 117.682 us; speedup vs baseline: 1.5320x; 1.5320x over previous
//
#include <hip/hip_runtime.h>
#include <hip/hip_bf16.h>

// MHA: B=2, S=2048, D=1024, H=16, dk=64.  M = B*S = 4096.
// ws: 0 Wt_q | 2MB Wt_k | 4MB Wt_v | 6MB Wt_o (bf16 [out][in])
//     8MB Q2 [M,1024] bf16 (pre-scaled 0.125*log2e) | 16MB K2 [M,1024]
//     24MB Vt [B,H,64,S] | 32MB ctx [M,1024]
//     40MB Opart bf16 [2][65536][64] (16MB) | 57MB lpart f32 [2][65536]
// (exact round-11 configuration — best measured: 117.9 us)

typedef __bf16 bf16x8 __attribute__((ext_vector_type(8)));
typedef float  f32x4  __attribute__((ext_vector_type(4)));

#define DEVI __device__ __forceinline__
#define SWZ(row, cb) ((cb) ^ (((row) & 7) << 4))

#define GLOAD16(gsrc, ldst)                                                    \
    __builtin_amdgcn_global_load_lds(                                          \
        (const __attribute__((address_space(1))) unsigned int*)(gsrc),         \
        (__attribute__((address_space(3))) unsigned int*)(ldst), 16, 0, 0)

// raw barrier: NO implicit vmcnt(0) drain (unlike __syncthreads)
#define BAR()        asm volatile("s_barrier" ::: "memory")
#define WAIT_LGKM0() asm volatile("s_waitcnt lgkmcnt(0)" ::: "memory")
#define WAIT_VM0()   asm volatile("s_waitcnt vmcnt(0)" ::: "memory")
#define WAIT_VM2()   asm volatile("s_waitcnt vmcnt(2)" ::: "memory")

static DEVI unsigned short f2bf(float f) {
    __hip_bfloat16 h = __float2bfloat16(f);
    return __builtin_bit_cast(unsigned short, h);
}
// single-instruction packed f32->bf16 (RNE), T12 recipe
static DEVI unsigned int cvt2(float lo, float hi) {
    unsigned int r;
    asm("v_cvt_pk_bf16_f32 %0, %1, %2" : "=v"(r) : "v"(lo), "v"(hi));
    return r;
}
static DEVI float bf2f(unsigned int lo16) {
    unsigned int x = lo16 << 16;
    return __builtin_bit_cast(float, x);
}
static DEVI bf16x8 ldsRead(const char* p) {
    return __builtin_bit_cast(bf16x8, *(const uint4*)p);
}

// ---------------------------------------------------------------------------
// Kernel 1: weight transpose + bf16 convert
// ---------------------------------------------------------------------------
__global__ __launch_bounds__(256) void wtrans_kernel(
    const float* w0, const float* w1, const float* w2, const float* w3,
    unsigned short* t0, unsigned short* t1, unsigned short* t2, unsigned short* t3)
{
    __shared__ unsigned short tile[64][80];
    const int z = blockIdx.z;
    const float* w = (z == 0) ? w0 : (z == 1) ? w1 : (z == 2) ? w2 : w3;
    unsigned short* wt = (z == 0) ? t0 : (z == 1) ? t1 : (z == 2) ? t2 : t3;
    const int n0 = blockIdx.x * 64, k0 = blockIdx.y * 64;
    const int t = threadIdx.x;
#pragma unroll
    for (int i = 0; i < 4; i++) {
        int chunk = t + i * 256;
        int row = chunk >> 4, c4 = chunk & 15;
        float4 v = *(const float4*)(w + (size_t)(k0 + row) * 1024 + n0 + c4 * 4);
        tile[c4 * 4 + 0][row] = f2bf(v.x);
        tile[c4 * 4 + 1][row] = f2bf(v.y);
        tile[c4 * 4 + 2][row] = f2bf(v.z);
        tile[c4 * 4 + 3][row] = f2bf(v.w);
    }
    __syncthreads();
#pragma unroll
    for (int i = 0; i < 2; i++) {
        int idx = t + i * 256;
        int row = idx >> 3, ch = idx & 7;
        uint4 vv = *(const uint4*)(&tile[row][ch * 8]);
        *(uint4*)(wt + (size_t)(n0 + row) * 1024 + k0 + ch * 8) = vv;
    }
}

// ---------------------------------------------------------------------------
// Kernel 2: QKV projections (round 11 — f32 A raw-staged via gload_lds,
// reg-convert with cvt_pk; B bf16 gload_lds; 48KB LDS, 3 blocks/CU).
// ---------------------------------------------------------------------------
__global__ __launch_bounds__(256, 3) void gemm_proj_kernel(
    const float* x0, const float* x1, const float* x2,
    const unsigned short* wt0, const unsigned short* wt1, const unsigned short* wt2,
    const float* b0, const float* b1, const float* b2,
    unsigned short* y0, unsigned short* y1, unsigned short* y2)
{
    __shared__ __align__(16) char Af[32768];   // f32 [128][64], swizzled
    __shared__ __align__(16) char Bs[16384];   // bf16 [128][64], swizzled
    const int i = blockIdx.x;
    const int xcd = i & 7, j = i >> 3;          // j 0..95
    const int panel = xcd * 12 + (j >> 3);      // 96 panels = 3z x 32m
    const int z = panel >> 5, mblk = panel & 31;
    const int n0 = (j & 7) * 128, m0 = mblk * 128;

    const float* X = (z == 0) ? x0 : (z == 1) ? x1 : x2;
    const unsigned short* Wt = (z == 0) ? wt0 : (z == 1) ? wt1 : wt2;
    const float* bias = (z == 0) ? b0 : (z == 1) ? b1 : b2;
    unsigned short* Y = (z == 0) ? y0 : (z == 1) ? y1 : y2;
    const float scale = (z == 0) ? 0.125f * 1.44269504f : 1.0f;
    const int t = threadIdx.x, w = t >> 6, l = t & 63, l15 = l & 15, l4 = l >> 4;
    const int wr = w >> 1, wc = w & 1;
    const char* Ab = (const char*)X;
    const char* Bb = (const char*)Wt;

    f32x4 acc[4][4];
#pragma unroll
    for (int mr = 0; mr < 4; mr++)
#pragma unroll
        for (int nc = 0; nc < 4; nc++) acc[mr][nc] = f32x4{0.f, 0.f, 0.f, 0.f};

#pragma unroll 1
    for (int k = 0; k < 16; ++k) {
        const int k0 = k * 64;
        BAR();  // all waves done reading previous tiles
#pragma unroll
        for (int jj = 0; jj < 8; jj++) {
            int o = w * 8192 + jj * 1024 + l * 16;
            int row = o >> 8, cb = (o >> 4) & 15;
            int csw = cb ^ ((row & 7) << 1);
            GLOAD16(Ab + ((size_t)(m0 + row) * 1024 + k0 + csw * 4) * 4,
                    Af + w * 8192 + jj * 1024);
        }
#pragma unroll
        for (int jj = 0; jj < 4; jj++) {
            int o = w * 4096 + jj * 1024 + l * 16;
            int row = o >> 7, cb = (o >> 4) & 7;
            int csw = cb ^ (row & 7);
            GLOAD16(Bb + ((size_t)(n0 + row) * 1024 + k0 + csw * 8) * 2,
                    Bs + w * 4096 + jj * 1024);
        }
        WAIT_VM0();
        BAR();

        bf16x8 af[4][2], bfr[4][2];
#pragma unroll
        for (int mr = 0; mr < 4; mr++) {
            int row = wr * 64 + mr * 16 + l15;
            int x = (row & 7) << 1;
#pragma unroll
            for (int kf = 0; kf < 2; kf++) {
                int cb = kf * 8 + l4 * 2;
                const char* p = Af + row * 256 + (cb ^ x) * 16;  // 32B contiguous
                float4 a = *(const float4*)p;
                float4 b = *(const float4*)(p + 16);
                uint4 pk = {cvt2(a.x, a.y), cvt2(a.z, a.w),
                            cvt2(b.x, b.y), cvt2(b.z, b.w)};
                af[mr][kf] = __builtin_bit_cast(bf16x8, pk);
            }
        }
#pragma unroll
        for (int nc = 0; nc < 4; nc++) {
            int row = wc * 64 + nc * 16 + l15;
#pragma unroll
            for (int kf = 0; kf < 2; kf++)
                bfr[nc][kf] = ldsRead(Bs + row * 128 + SWZ(row, kf * 64 + l4 * 16));
        }
        __builtin_amdgcn_s_setprio(1);
#pragma unroll
        for (int kf = 0; kf < 2; kf++)
#pragma unroll
            for (int mr = 0; mr < 4; mr++)
#pragma unroll
                for (int nc = 0; nc < 4; nc++)
                    acc[mr][nc] = __builtin_amdgcn_mfma_f32_16x16x32_bf16(
                        af[mr][kf], bfr[nc][kf], acc[mr][nc], 0, 0, 0);
        __builtin_amdgcn_s_setprio(0);
    }

    WAIT_LGKM0();
    BAR();  // all waves done with Af before reuse as epilogue buffer
    char* Es = Af;  // 32KB: [128][128] bf16
    if (z < 2) {
#pragma unroll
        for (int nc = 0; nc < 4; nc++) {
            float bv = bias[n0 + wc * 64 + nc * 16 + l15];
#pragma unroll
            for (int mr = 0; mr < 4; mr++) {
#pragma unroll
                for (int r = 0; r < 2; r++) {
                    int mloc = wr * 64 + mr * 16 + l4 * 4 + r * 2;
                    int nloc = wc * 64 + nc * 16 + l15;
                    unsigned int pk = cvt2((acc[mr][nc][r * 2] + bv) * scale,
                                           (acc[mr][nc][r * 2 + 1] + bv) * scale);
                    *(unsigned short*)(Es + mloc * 256 + nloc * 2) =
                        (unsigned short)(pk & 0xffff);
                    *(unsigned short*)(Es + (mloc + 1) * 256 + nloc * 2) =
                        (unsigned short)(pk >> 16);
                }
            }
        }
        WAIT_LGKM0();
        BAR();
#pragma unroll
        for (int ii = 0; ii < 8; ii++) {
            int idx = t + ii * 256, row = idx >> 4, ch = idx & 15;
            *(uint4*)((char*)Y + ((size_t)(m0 + row) * 1024 + n0 + ch * 8) * 2) =
                *(const uint4*)(Es + row * 256 + ch * 16);
        }
    } else {
#pragma unroll
        for (int nc = 0; nc < 4; nc++) {
            float bv = bias[n0 + wc * 64 + nc * 16 + l15];
#pragma unroll
            for (int mr = 0; mr < 4; mr++) {
#pragma unroll
                for (int r = 0; r < 2; r++) {
                    int mloc = wr * 64 + mr * 16 + l4 * 4 + r * 2;
                    int nloc = wc * 64 + nc * 16 + l15;
                    unsigned int pk = cvt2(acc[mr][nc][r * 2] + bv,
                                           acc[mr][nc][r * 2 + 1] + bv);
                    // transpose layout [128 n][128 m]: adjacent m adjacent u16
                    *(unsigned int*)(Es + nloc * 256 + mloc * 2) = pk;
                }
            }
        }
        WAIT_LGKM0();
        BAR();
        const int bb = m0 >> 11, s0 = m0 & 2047;
#pragma unroll
        for (int ii = 0; ii < 8; ii++) {
            int idx = t + ii * 256, row = idx >> 4, ch = idx & 15;
            int col = n0 + row, h = col >> 6, d = col & 63;
            *(uint4*)((char*)Y +
                      (((size_t)((bb * 16 + h) * 64 + d)) * 2048 + s0 + ch * 8) * 2) =
                *(const uint4*)(Es + row * 256 + ch * 16);
        }
    }
}

// ---------------------------------------------------------------------------
// Kernel 3: flash attention, SPLIT-K (round 11).
// ---------------------------------------------------------------------------
__global__ __launch_bounds__(256, 4) void attn_kernel(
    const unsigned short* Q2, const unsigned short* K2, const unsigned short* VT,
    unsigned short* Opart, float* lpart)
{
    __shared__ __align__(16) char sm[40960];
    char* Pall = sm;                    // 16KB: per-wave P (4KB each)
    char* K0s = sm + 16384;
    char* K1s = sm + 24576;
    char* Vs  = sm + 32768;
    const int t = threadIdx.x, w = t >> 6, l = t & 63, l15 = l & 15, l4 = l >> 4;
    char* Ps = Pall + w * 4096;         // 32 rows x 128B per wave

    // mapping: 8 XCD x 4 heads x (16 qblk x 2 khalf)
    const int i = blockIdx.x;
    const int xcd = i & 7, j = i >> 3;          // j 0..127
    const int bh = xcd * 4 + (j >> 5);
    const int jj = j & 31, qblk = jj >> 1, kh = jj & 1;
    const int b = bh >> 4, h = bh & 15;
    const int q0 = qblk * 128;
    const char* Qb = (const char*)(Q2 + ((size_t)(b * 2048 + q0)) * 1024 + h * 64);
    const char* Kb = (const char*)(K2 + ((size_t)(b * 2048)) * 1024 + h * 64);
    const char* Vb = (const char*)(VT + (size_t)bh * 64 * 2048);

    int kGO[2], vGO[2];
#pragma unroll
    for (int jj2 = 0; jj2 < 2; jj2++) {
        int row = w * 16 + jj2 * 8 + (l >> 3);
        int ch = (l & 7) ^ (row & 7);
        kGO[jj2] = row * 2048 + ch * 16;
        vGO[jj2] = row * 4096 + ch * 16;
    }
    int kRO[4][2];
#pragma unroll
    for (int cc = 0; cc < 4; cc++) {
        int row = cc * 16 + l15;
#pragma unroll
        for (int kf = 0; kf < 2; kf++)
            kRO[cc][kf] = row * 128 + SWZ(row, kf * 64 + l4 * 16);
    }
    int pWO[2][4], pRO[2][2];
#pragma unroll
    for (int qi = 0; qi < 2; qi++) {
        int row = qi * 16 + l15;
#pragma unroll
        for (int cc = 0; cc < 4; cc++) {
            int c = (cc * 2 + (l4 >> 1)) ^ (l15 & 7);
            pWO[qi][cc] = row * 128 + c * 16 + (l4 & 1) * 8;
        }
#pragma unroll
        for (int kf = 0; kf < 2; kf++)
            pRO[qi][kf] = row * 128 + SWZ(row, kf * 64 + l4 * 16);
    }

#define STAGE_K(TT, Kdst)                                                      \
    do {                                                                       \
        int kk0 = (TT) * 64;                                                   \
        _Pragma("unroll") for (int s2 = 0; s2 < 2; s2++)                       \
            GLOAD16(Kb + (size_t)(kk0 * 2048 + kGO[s2]),                       \
                    (Kdst) + w * 2048 + s2 * 1024);                            \
    } while (0)
#define STAGE_V(TT)                                                            \
    do {                                                                       \
        int kk0 = (TT) * 64;                                                   \
        _Pragma("unroll") for (int s2 = 0; s2 < 2; s2++)                       \
            GLOAD16(Vb + (size_t)(kk0 * 2 + vGO[s2]),                          \
                    Vs + w * 2048 + s2 * 1024);                                \
    } while (0)

    bf16x8 qf[2][2];
#pragma unroll
    for (int qi = 0; qi < 2; qi++) {
        int row = w * 32 + qi * 16 + l15;
#pragma unroll
        for (int kf = 0; kf < 2; kf++)
            qf[qi][kf] = __builtin_bit_cast(
                bf16x8, *(const uint4*)(Qb + (size_t)row * 2048 + kf * 64 + l4 * 16));
    }

    const int tbase = kh * 16;
    STAGE_K(tbase + (qblk & 15), K0s);
    STAGE_V(tbase + (qblk & 15));
    WAIT_VM0();
    BAR();

    bf16x8 ones;
#pragma unroll
    for (int e = 0; e < 8; e++) ones[e] = (__bf16)1.0f;

    f32x4 o[2][4], ol[2];
#pragma unroll
    for (int qi = 0; qi < 2; qi++) {
#pragma unroll
        for (int c = 0; c < 4; c++) o[qi][c] = f32x4{0.f, 0.f, 0.f, 0.f};
        ol[qi] = f32x4{0.f, 0.f, 0.f, 0.f};
    }

#pragma unroll 1
    for (int it = 0; it < 16; it++) {
        char* Kc = (it & 1) ? K1s : K0s;
        char* Kn = (it & 1) ? K0s : K1s;
        if (it < 15) STAGE_K(tbase + ((qblk + it + 1) & 15), Kn);

        f32x4 sacc[2][4];
#pragma unroll
        for (int qi = 0; qi < 2; qi++)
#pragma unroll
            for (int c = 0; c < 4; c++) sacc[qi][c] = f32x4{0.f, 0.f, 0.f, 0.f};
        __builtin_amdgcn_s_setprio(1);
#pragma unroll
        for (int cc = 0; cc < 4; cc++)
#pragma unroll
            for (int kf = 0; kf < 2; kf++) {
                bf16x8 kfrag = ldsRead(Kc + kRO[cc][kf]);
#pragma unroll
                for (int qi = 0; qi < 2; qi++)
                    sacc[qi][cc] = __builtin_amdgcn_mfma_f32_16x16x32_bf16(
                        kfrag, qf[qi][kf], sacc[qi][cc], 0, 0, 0);
            }
        __builtin_amdgcn_s_setprio(0);

#pragma unroll
        for (int qi = 0; qi < 2; qi++)
#pragma unroll
            for (int cc = 0; cc < 4; cc++)
#pragma unroll
                for (int r = 0; r < 4; r++)
                    sacc[qi][cc][r] = __builtin_amdgcn_exp2f(sacc[qi][cc][r]);

#pragma unroll
        for (int qi = 0; qi < 2; qi++)
#pragma unroll
            for (int cc = 0; cc < 4; cc++) {
                uint2 pk = {cvt2(sacc[qi][cc][0], sacc[qi][cc][1]),
                            cvt2(sacc[qi][cc][2], sacc[qi][cc][3])};
                *(uint2*)(Ps + pWO[qi][cc]) = pk;
            }
        asm volatile("" ::: "memory");
        bf16x8 pf[2][2];
#pragma unroll
        for (int qi = 0; qi < 2; qi++)
#pragma unroll
            for (int kf = 0; kf < 2; kf++)
                pf[qi][kf] = ldsRead(Ps + pRO[qi][kf]);

        if (it < 15) { WAIT_VM2(); } else { WAIT_VM0(); }
        BAR();

        __builtin_amdgcn_s_setprio(1);
#pragma unroll
        for (int dd = 0; dd < 4; dd++)
#pragma unroll
            for (int kf = 0; kf < 2; kf++) {
                bf16x8 vfrag = ldsRead(Vs + kRO[dd][kf]);
#pragma unroll
                for (int qi = 0; qi < 2; qi++)
                    o[qi][dd] = __builtin_amdgcn_mfma_f32_16x16x32_bf16(
                        vfrag, pf[qi][kf], o[qi][dd], 0, 0, 0);
            }
#pragma unroll
        for (int qi = 0; qi < 2; qi++)
#pragma unroll
            for (int kf = 0; kf < 2; kf++)
                ol[qi] = __builtin_amdgcn_mfma_f32_16x16x32_bf16(
                    ones, pf[qi][kf], ol[qi], 0, 0, 0);
        __builtin_amdgcn_s_setprio(0);

        WAIT_LGKM0();
        BAR();
        if (it < 15) {
            STAGE_V(tbase + ((qblk + it + 1) & 15));
            WAIT_VM2();
            BAR();
        }
    }
#undef STAGE_K
#undef STAGE_V

    const size_t qgbase = (size_t)bh * 2048 + q0 + w * 32;
#pragma unroll
    for (int qi = 0; qi < 2; qi++) {
        size_t qg = qgbase + qi * 16 + l15;
        unsigned short* orow = Opart + ((size_t)kh * 65536 + qg) * 64;
#pragma unroll
        for (int dd = 0; dd < 4; dd++) {
            uint2 pk = {cvt2(o[qi][dd][0], o[qi][dd][1]),
                        cvt2(o[qi][dd][2], o[qi][dd][3])};
            *(uint2*)(orow + dd * 16 + l4 * 4) = pk;
        }
        if (l4 == 0) lpart[(size_t)kh * 65536 + qg] = ol[qi][0];
    }
}

// ---------------------------------------------------------------------------
// Kernel 3b: combine split-K partials -> ctx bf16 [B,S,1024]
// ---------------------------------------------------------------------------
__global__ __launch_bounds__(256) void reduce_kernel(
    const unsigned short* Op, const float* lp, unsigned short* ctx)
{
    int idx = blockIdx.x * 256 + threadIdx.x;   // 524288 total
    int qg = idx >> 3, c8 = idx & 7;
    uint4 a = *(const uint4*)(Op + (size_t)qg * 64 + c8 * 8);
    uint4 bq = *(const uint4*)(Op + (size_t)65536 * 64 + (size_t)qg * 64 + c8 * 8);
    float rinv = 1.0f / (lp[qg] + lp[65536 + qg]);
    const unsigned int* pa = (const unsigned int*)&a;
    const unsigned int* pb = (const unsigned int*)&bq;
    unsigned int outp[4];
#pragma unroll
    for (int j = 0; j < 4; j++) {
        float s0 = (bf2f(pa[j] & 0xffff) + bf2f(pb[j] & 0xffff)) * rinv;
        float s1 = (bf2f(pa[j] >> 16) + bf2f(pb[j] >> 16)) * rinv;
        outp[j] = cvt2(s0, s1);
    }
    int bh = qg >> 11, s = qg & 2047, b = bh >> 4, h = bh & 15;
    *(uint4*)(ctx + ((size_t)(b * 2048 + s)) * 1024 + h * 64 + c8 * 8) =
        *(const uint4*)outp;
}

// ---------------------------------------------------------------------------
// Kernel 4: output projection, m97 structure (round 11).
// ---------------------------------------------------------------------------
__global__ __launch_bounds__(256, 3) void gemm_out_kernel(
    const unsigned short* ctx, const unsigned short* wto, const float* bias, float* out)
{
    __shared__ __align__(16) char As[16384];
    __shared__ __align__(16) char Bs[16384];
    const int i = blockIdx.x;
    const int xcd = i & 7, j = i >> 3;          // j 0..31
    const int mpanel = xcd * 4 + (j >> 3);
    const int n0 = (j & 7) * 128, m0 = mpanel * 128;
    const int t = threadIdx.x, w = t >> 6, l = t & 63, l15 = l & 15, l4 = l >> 4;
    const int wr = w >> 1, wc = w & 1;
    const char* Ab = (const char*)ctx;
    const char* Bb = (const char*)wto;

    f32x4 acc[4][4];
#pragma unroll
    for (int mr = 0; mr < 4; mr++)
#pragma unroll
        for (int nc = 0; nc < 4; nc++) acc[mr][nc] = f32x4{0.f, 0.f, 0.f, 0.f};

#pragma unroll 1
    for (int k = 0; k < 16; ++k) {
        const int k0 = k * 64;
        BAR();
#pragma unroll
        for (int jj = 0; jj < 4; jj++) {
            int o = w * 4096 + jj * 1024 + l * 16;
            int row = o >> 7, cb = (o >> 4) & 7;
            int csw = cb ^ (row & 7);
            GLOAD16(Ab + ((size_t)(m0 + row) * 1024 + k0 + csw * 8) * 2,
                    As + w * 4096 + jj * 1024);
        }
#pragma unroll
        for (int jj = 0; jj < 4; jj++) {
            int o = w * 4096 + jj * 1024 + l * 16;
            int row = o >> 7, cb = (o >> 4) & 7;
            int csw = cb ^ (row & 7);
            GLOAD16(Bb + ((size_t)(n0 + row) * 1024 + k0 + csw * 8) * 2,
                    Bs + w * 4096 + jj * 1024);
        }
        WAIT_VM0();
        BAR();

        bf16x8 af[4][2], bfr[4][2];
#pragma unroll
        for (int mr = 0; mr < 4; mr++) {
            int row = wr * 64 + mr * 16 + l15;
#pragma unroll
            for (int kf = 0; kf < 2; kf++)
                af[mr][kf] = ldsRead(As + row * 128 + SWZ(row, kf * 64 + l4 * 16));
        }
#pragma unroll
        for (int nc = 0; nc < 4; nc++) {
            int row = wc * 64 + nc * 16 + l15;
#pragma unroll
            for (int kf = 0; kf < 2; kf++)
                bfr[nc][kf] = ldsRead(Bs + row * 128 + SWZ(row, kf * 64 + l4 * 16));
        }
        __builtin_amdgcn_s_setprio(1);
#pragma unroll
        for (int kf = 0; kf < 2; kf++)
#pragma unroll
            for (int mr = 0; mr < 4; mr++)
#pragma unroll
                for (int nc = 0; nc < 4; nc++)
                    acc[mr][nc] = __builtin_amdgcn_mfma_f32_16x16x32_bf16(
                        af[mr][kf], bfr[nc][kf], acc[mr][nc], 0, 0, 0);
        __builtin_amdgcn_s_setprio(0);
    }

#pragma unroll
    for (int nc = 0; nc < 4; nc++) {
        int col = n0 + wc * 64 + nc * 16 + l15;
        float bv = bias[col];
#pragma unroll
        for (int mr = 0; mr < 4; mr++)
#pragma unroll
            for (int r = 0; r < 4; r++) {
                int m = m0 + wr * 64 + mr * 16 + l4 * 4 + r;
                out[(size_t)m * 1024 + col] = acc[mr][nc][r] + bv;
            }
    }
}

// ---------------------------------------------------------------------------
extern "C" void kernel_launch(void* const* d_in, const int* in_sizes, int n_in,
                              void* d_out, int out_size, void* d_ws, size_t ws_size,
                              hipStream_t stream)
{
    (void)in_sizes; (void)n_in; (void)out_size; (void)ws_size;
    const float* q  = (const float*)d_in[0];
    const float* k  = (const float*)d_in[1];
    const float* v  = (const float*)d_in[2];
    const float* wq = (const float*)d_in[3];
    const float* bq = (const float*)d_in[4];
    const float* wk = (const float*)d_in[5];
    const float* bk = (const float*)d_in[6];
    const float* wv = (const float*)d_in[7];
    const float* bv = (const float*)d_in[8];
    const float* wo = (const float*)d_in[9];
    const float* bo = (const float*)d_in[10];

    char* ws = (char*)d_ws;
    const size_t MB = 1u << 20;
    unsigned short* WTq = (unsigned short*)(ws + 0 * MB);
    unsigned short* WTk = (unsigned short*)(ws + 2 * MB);
    unsigned short* WTv = (unsigned short*)(ws + 4 * MB);
    unsigned short* WTo = (unsigned short*)(ws + 6 * MB);
    unsigned short* Q2  = (unsigned short*)(ws + 8 * MB);
    unsigned short* K2  = (unsigned short*)(ws + 16 * MB);
    unsigned short* VT  = (unsigned short*)(ws + 24 * MB);
    unsigned short* CTX = (unsigned short*)(ws + 32 * MB);
    unsigned short* OPART = (unsigned short*)(ws + 40 * MB);
    float*          LPART = (float*)(ws + 57 * MB);

    wtrans_kernel<<<dim3(16, 16, 4), 256, 0, stream>>>(wq, wk, wv, wo, WTq, WTk, WTv, WTo);
    gemm_proj_kernel<<<768, 256, 0, stream>>>(q, k, v, WTq, WTk, WTv,
                                              bq, bk, bv, Q2, K2, VT);
    attn_kernel<<<1024, 256, 0, stream>>>(Q2, K2, VT, OPART, LPART);
    reduce_kernel<<<2048, 256, 0, stream>>>(OPART, LPART, CTX);
    gemm_out_kernel<<<256, 256, 0, stream>>>(CTX, WTo, bo, (float*)d_out);
}